// Round 4
// baseline (1435.605 us; speedup 1.0000x reference)
//
#include <hip/hip_runtime.h>
#include <hip/hip_bf16.h>

constexpr int NN    = 30000;   // total nodes
constexpr int NCELL = 66;
constexpr int NF    = 256;     // features
constexpr float EPS = 1e-5f;

// ---------------- init: deg=1 (self loop), counts/fill/sums = 0 ----------------
__global__ void k_init(float* deg, int* counts, int* fill, float* sums) {
    int i = blockIdx.x * 256 + threadIdx.x;
    if (i < NN) { deg[i] = 1.0f; counts[i] = 0; fill[i] = 0; }
    if (i < 2 * NF) sums[i] = 0.0f;
}

__global__ void k_zero_stats(float* sums) {
    int i = threadIdx.x;
    if (i < 2 * NF) sums[i] = 0.0f;
}

// ---------------- concat input (cell ++ sub), float4 ----------------
__global__ void k_concat(const float4* __restrict__ cell, const float4* __restrict__ sub,
                         float4* __restrict__ x) {
    int idx = blockIdx.x * 256 + threadIdx.x;          // float4 index
    if (idx >= NN * (NF / 4)) return;
    const int CELL4 = NCELL * (NF / 4);
    x[idx] = (idx < CELL4) ? cell[idx] : sub[idx - CELL4];
}

// ---------------- degree + per-col edge counts ----------------
__global__ void k_pass1(const int* __restrict__ ei, const float* __restrict__ ew,
                        float* deg, int* counts, int E) {
    int e = blockIdx.x * 256 + threadIdx.x;
    if (e >= E) return;
    int col = ei[E + e];
    atomicAdd(&deg[col], ew[e]);
    atomicAdd(&counts[col], 1);
}

__global__ void k_dinv(const float* __restrict__ deg, float* __restrict__ dinv) {
    int i = blockIdx.x * 256 + threadIdx.x;
    if (i < NN) dinv[i] = rsqrtf(deg[i]);   // deg >= 1 always (self loop)
}

// ---------------- exclusive prefix sum of counts -> col_ptr (single block) --------
__global__ void k_scan(const int* __restrict__ counts, int* __restrict__ col_ptr) {
    __shared__ int part[256];
    __shared__ int pref[257];
    int t = threadIdx.x;
    const int CH = (NN + 255) / 256;   // 118
    int beg = t * CH;
    int end = beg + CH; if (end > NN) end = NN;
    int s = 0;
    for (int i = beg; i < end; i++) s += counts[i];
    part[t] = s;
    __syncthreads();
    if (t == 0) {
        int r = 0;
        for (int i = 0; i < 256; i++) { pref[i] = r; r += part[i]; }
        pref[256] = r;
    }
    __syncthreads();
    int run = pref[t];
    for (int i = beg; i < end; i++) { col_ptr[i] = run; run += counts[i]; }
    if (t == 255) col_ptr[NN] = pref[256];
}

// ---------------- scatter edges into CSR (sorted by col), compute norm ------------
__global__ void k_scatter(const int* __restrict__ ei, const float* __restrict__ ew,
                          const float* __restrict__ dinv, const int* __restrict__ col_ptr,
                          int* fill, int* __restrict__ rs, float* __restrict__ ns, int E) {
    int e = blockIdx.x * 256 + threadIdx.x;
    if (e >= E) return;
    int row = ei[e];
    int col = ei[E + e];
    float nrm = dinv[row] * ew[e] * dinv[col];
    int pos = col_ptr[col] + atomicAdd(&fill[col], 1);
    rs[pos] = row;
    ns[pos] = nrm;
}

// ---------------- one propagation hop: y = A_hat x (gather form) ----------------
__global__ __launch_bounds__(64) void k_prop(const float* __restrict__ xin,
                                             float* __restrict__ xout,
                                             const int* __restrict__ col_ptr,
                                             const int* __restrict__ rs,
                                             const float* __restrict__ ns,
                                             const float* __restrict__ dinv) {
    int n = blockIdx.x;
    int t = threadIdx.x;               // 64 threads, each owns 4 features
    const float4* x4 = (const float4*)xin;
    float dn = dinv[n];
    float sl = dn * dn;                // self-loop norm
    float4 v = x4[n * 64 + t];
    float4 acc;
    acc.x = sl * v.x; acc.y = sl * v.y; acc.z = sl * v.z; acc.w = sl * v.w;
    int beg = col_ptr[n], end = col_ptr[n + 1];
    for (int e = beg; e < end; ++e) {
        int src = rs[e];
        float w = ns[e];
        float4 u = x4[src * 64 + t];
        acc.x += w * u.x; acc.y += w * u.y; acc.z += w * u.z; acc.w += w * u.w;
    }
    ((float4*)xout)[n * 64 + t] = acc;
}

// ---------------- y = x @ W^T + b   (out[n][o] = b[o] + sum_k x[n][k]*W[o][k]) ----
__global__ __launch_bounds__(256) void k_gemm(const float* __restrict__ x,
                                              const float* __restrict__ W,
                                              const float* __restrict__ bias,
                                              float* __restrict__ y) {
    __shared__ float xs[8][NF];
    int t = threadIdx.x;               // output feature o
    int base = blockIdx.x * 8;         // 8 nodes per block
    #pragma unroll
    for (int j = 0; j < 8; j++) xs[j][t] = x[(base + j) * NF + t];
    __syncthreads();
    float acc[8];
    float bb = bias[t];
    #pragma unroll
    for (int j = 0; j < 8; j++) acc[j] = bb;
    const float* wr = W + t * NF;
    for (int k = 0; k < NF; k++) {
        float w = wr[k];
        #pragma unroll
        for (int j = 0; j < 8; j++) acc[j] += xs[j][k] * w;
    }
    #pragma unroll
    for (int j = 0; j < 8; j++) y[(base + j) * NF + t] = acc[j];
}

// ---------------- PReLU in place + per-feature sum/sumsq partials ----------------
__global__ __launch_bounds__(256) void k_prelu_stats(float* __restrict__ x,
                                                     const float* __restrict__ pw,
                                                     float* __restrict__ sums) {
    int t = threadIdx.x;               // feature
    float p = pw[t];
    float s = 0.f, s2 = 0.f;
    for (int n = blockIdx.x; n < NN; n += gridDim.x) {
        float v = x[n * NF + t];
        v = (v >= 0.f) ? v : p * v;
        x[n * NF + t] = v;
        s += v; s2 += v * v;
    }
    atomicAdd(&sums[t], s);
    atomicAdd(&sums[NF + t], s2);
}

// ---------------- finalize BN scale/shift ----------------
__global__ void k_finalize(const float* __restrict__ sums, const float* __restrict__ gamma,
                           const float* __restrict__ beta, float* __restrict__ ss) {
    int t = threadIdx.x;
    float mean = sums[t] / (float)NN;
    float var = sums[NF + t] / (float)NN - mean * mean;
    if (var < 0.f) var = 0.f;
    float istd = rsqrtf(var + EPS);
    float sc = gamma[t] * istd;
    ss[t] = sc;
    ss[NF + t] = beta[t] - mean * sc;
}

// ---------------- apply BN (layer 1, in place, f32) ----------------
__global__ void k_apply_f32(float* __restrict__ x, const float* __restrict__ ss) {
    int idx = blockIdx.x * 256 + threadIdx.x;
    if (idx >= NN * NF) return;
    int t = idx & (NF - 1);
    x[idx] = x[idx] * ss[t] + ss[NF + t];
}

// ---------------- apply BN (layer 2) + write FLOAT32 output ----------------
__global__ void k_apply_out(const float* __restrict__ x, const float* __restrict__ ss,
                            float* __restrict__ out) {
    int idx = blockIdx.x * 256 + threadIdx.x;
    if (idx >= NN * NF) return;
    int t = idx & (NF - 1);
    out[idx] = x[idx] * ss[t] + ss[NF + t];
}

extern "C" void kernel_launch(void* const* d_in, const int* in_sizes, int n_in,
                              void* d_out, int out_size, void* d_ws, size_t ws_size,
                              hipStream_t stream) {
    const float* cell  = (const float*)d_in[0];
    const float* sub   = (const float*)d_in[1];
    const int*   ei    = (const int*)  d_in[2];
    const float* ew    = (const float*)d_in[3];
    const float* W1    = (const float*)d_in[4];
    const float* bias1 = (const float*)d_in[5];
    const float* W2    = (const float*)d_in[6];
    const float* bias2 = (const float*)d_in[7];
    const float* pw    = (const float*)d_in[8];
    const float* gamma = (const float*)d_in[9];
    const float* beta  = (const float*)d_in[10];
    float* out = (float*)d_out;        // reference output dtype is float32
    const int E = in_sizes[3];         // 960000 directed edges

    char* ws = (char*)d_ws;
    size_t off = 0;
    auto alloc = [&](size_t bytes) -> void* {
        void* p = ws + off;
        off = (off + bytes + 255) & ~((size_t)255);
        return p;
    };
    float* xA      = (float*)alloc((size_t)NN * NF * 4);
    float* xB      = (float*)alloc((size_t)NN * NF * 4);
    float* deg     = (float*)alloc((size_t)NN * 4);
    float* dinv    = (float*)alloc((size_t)NN * 4);
    int*   counts  = (int*)  alloc((size_t)NN * 4);
    int*   col_ptr = (int*)  alloc((size_t)(NN + 1) * 4);
    int*   fill    = (int*)  alloc((size_t)NN * 4);
    int*   rs      = (int*)  alloc((size_t)E * 4);
    float* ns      = (float*)alloc((size_t)E * 4);
    float* sums    = (float*)alloc((size_t)2 * NF * 4);
    float* ss      = (float*)alloc((size_t)2 * NF * 4);

    const int gN  = (NN + 255) / 256;        // 118
    const int gE  = (E + 255) / 256;
    const int gNF = (NN * NF) / 256;         // 30000
    const int gV4 = (NN * NF / 4 + 255) / 256;

    k_init<<<gN, 256, 0, stream>>>(deg, counts, fill, sums);
    k_concat<<<gV4, 256, 0, stream>>>((const float4*)cell, (const float4*)sub, (float4*)xA);
    k_pass1<<<gE, 256, 0, stream>>>(ei, ew, deg, counts, E);
    k_dinv<<<gN, 256, 0, stream>>>(deg, dinv);
    k_scan<<<1, 256, 0, stream>>>(counts, col_ptr);
    k_scatter<<<gE, 256, 0, stream>>>(ei, ew, dinv, col_ptr, fill, rs, ns, E);

    // ---------------- layer 1 ----------------
    k_prop<<<NN, 64, 0, stream>>>(xA, xB, col_ptr, rs, ns, dinv);
    k_prop<<<NN, 64, 0, stream>>>(xB, xA, col_ptr, rs, ns, dinv);
    k_prop<<<NN, 64, 0, stream>>>(xA, xB, col_ptr, rs, ns, dinv);
    k_gemm<<<NN / 8, 256, 0, stream>>>(xB, W1, bias1, xA);
    k_prelu_stats<<<256, 256, 0, stream>>>(xA, pw, sums);
    k_finalize<<<1, 256, 0, stream>>>(sums, gamma, beta, ss);
    k_apply_f32<<<gNF, 256, 0, stream>>>(xA, ss);

    // ---------------- layer 2 ----------------
    k_zero_stats<<<1, 512, 0, stream>>>(sums);
    k_prop<<<NN, 64, 0, stream>>>(xA, xB, col_ptr, rs, ns, dinv);
    k_prop<<<NN, 64, 0, stream>>>(xB, xA, col_ptr, rs, ns, dinv);
    k_prop<<<NN, 64, 0, stream>>>(xA, xB, col_ptr, rs, ns, dinv);
    k_gemm<<<NN / 8, 256, 0, stream>>>(xB, W2, bias2, xA);
    k_prelu_stats<<<256, 256, 0, stream>>>(xA, pw, sums);
    k_finalize<<<1, 256, 0, stream>>>(sums, gamma, beta, ss);
    k_apply_out<<<gNF, 256, 0, stream>>>(xA, ss, out);
}

// Round 5
// 1070.690 us; speedup vs baseline: 1.3408x; 1.3408x over previous
//
#include <hip/hip_runtime.h>
#include <hip/hip_bf16.h>

constexpr int NN    = 30000;   // total nodes
constexpr int NCELL = 66;
constexpr int NF    = 256;     // features
constexpr float EPS = 1e-5f;

using bf16x8 = __attribute__((ext_vector_type(8))) short;   // 8 bf16 = 4 VGPRs
using f32x4  = __attribute__((ext_vector_type(4))) float;

__device__ __forceinline__ float bf2f(unsigned short u) {
    return __uint_as_float(((unsigned)u) << 16);
}
__device__ __forceinline__ unsigned short f2bf(float f) {
    __hip_bfloat16 h = __float2bfloat16(f);   // RNE
    return *reinterpret_cast<unsigned short*>(&h);
}

// ---------------- init: deg=1 (self loop), counts/fill/sums = 0 ----------------
__global__ void k_init(float* deg, int* counts, int* fill, float* sums) {
    int i = blockIdx.x * 256 + threadIdx.x;
    if (i < NN) { deg[i] = 1.0f; counts[i] = 0; fill[i] = 0; }
    if (i < 2 * NF) sums[i] = 0.0f;
}

__global__ void k_zero_stats(float* sums) {
    int i = threadIdx.x;
    if (i < 2 * NF) sums[i] = 0.0f;
}

// ---------------- concat (cell ++ sub) f32 -> bf16 ----------------
__global__ void k_concat_h(const float4* __restrict__ cell, const float4* __restrict__ sub,
                           ushort4* __restrict__ xh) {
    int idx = blockIdx.x * 256 + threadIdx.x;          // float4 index
    if (idx >= NN * (NF / 4)) return;
    const int CELL4 = NCELL * (NF / 4);
    float4 v = (idx < CELL4) ? cell[idx] : sub[idx - CELL4];
    ushort4 o;
    o.x = f2bf(v.x); o.y = f2bf(v.y); o.z = f2bf(v.z); o.w = f2bf(v.w);
    xh[idx] = o;
}

// ---------------- convert W (f32, o-major k-contig) -> bf16 ----------------
__global__ void k_cvtw(const float4* __restrict__ W, ushort4* __restrict__ Wh) {
    int idx = blockIdx.x * 256 + threadIdx.x;
    if (idx >= NF * NF / 4) return;
    float4 v = W[idx];
    ushort4 o;
    o.x = f2bf(v.x); o.y = f2bf(v.y); o.z = f2bf(v.z); o.w = f2bf(v.w);
    Wh[idx] = o;
}

// ---------------- degree + per-col edge counts ----------------
__global__ void k_pass1(const int* __restrict__ ei, const float* __restrict__ ew,
                        float* deg, int* counts, int E) {
    int e = blockIdx.x * 256 + threadIdx.x;
    if (e >= E) return;
    int col = ei[E + e];
    atomicAdd(&deg[col], ew[e]);
    atomicAdd(&counts[col], 1);
}

__global__ void k_dinv(const float* __restrict__ deg, float* __restrict__ dinv) {
    int i = blockIdx.x * 256 + threadIdx.x;
    if (i < NN) dinv[i] = rsqrtf(deg[i]);   // deg >= 1 always (self loop)
}

// ---------------- exclusive prefix sum of counts -> col_ptr (single block) --------
__global__ void k_scan(const int* __restrict__ counts, int* __restrict__ col_ptr) {
    __shared__ int part[256];
    __shared__ int pref[257];
    int t = threadIdx.x;
    const int CH = (NN + 255) / 256;   // 118
    int beg = t * CH;
    int end = beg + CH; if (end > NN) end = NN;
    int s = 0;
    for (int i = beg; i < end; i++) s += counts[i];
    part[t] = s;
    __syncthreads();
    if (t == 0) {
        int r = 0;
        for (int i = 0; i < 256; i++) { pref[i] = r; r += part[i]; }
        pref[256] = r;
    }
    __syncthreads();
    int run = pref[t];
    for (int i = beg; i < end; i++) { col_ptr[i] = run; run += counts[i]; }
    if (t == 255) col_ptr[NN] = pref[256];
}

// ---------------- scatter edges into CSR (sorted by col), compute norm ------------
__global__ void k_scatter(const int* __restrict__ ei, const float* __restrict__ ew,
                          const float* __restrict__ dinv, const int* __restrict__ col_ptr,
                          int* fill, int* __restrict__ rs, float* __restrict__ ns, int E) {
    int e = blockIdx.x * 256 + threadIdx.x;
    if (e >= E) return;
    int row = ei[e];
    int col = ei[E + e];
    float nrm = dinv[row] * ew[e] * dinv[col];
    int pos = col_ptr[col] + atomicAdd(&fill[col], 1);
    rs[pos] = row;
    ns[pos] = nrm;
}

// ------------- one hop: y = A_hat x, bf16 in/out, f32 accum, 4 waves/node ---------
__global__ __launch_bounds__(256) void k_prop(const ushort4* __restrict__ xin,
                                              ushort4* __restrict__ xout,
                                              const int* __restrict__ col_ptr,
                                              const int* __restrict__ rs,
                                              const float* __restrict__ ns,
                                              const float* __restrict__ dinv) {
    int n = blockIdx.x;
    int w = threadIdx.x >> 6;          // wave 0..3
    int t = threadIdx.x & 63;          // lane owns features 4t..4t+3
    int beg = col_ptr[n], end = col_ptr[n + 1];
    float4 acc = {0.f, 0.f, 0.f, 0.f};
    for (int e = beg + w; e < end; e += 4) {
        int src = rs[e];
        float wt = ns[e];
        ushort4 u = xin[src * 64 + t];
        acc.x += wt * bf2f(u.x);
        acc.y += wt * bf2f(u.y);
        acc.z += wt * bf2f(u.z);
        acc.w += wt * bf2f(u.w);
    }
    __shared__ float4 red[4][64];
    red[w][t] = acc;
    __syncthreads();
    if (w == 0) {
        float4 a = red[0][t], b = red[1][t], c = red[2][t], d = red[3][t];
        float dn = dinv[n];
        float sl = dn * dn;
        ushort4 u = xin[n * 64 + t];
        float rx = a.x + b.x + c.x + d.x + sl * bf2f(u.x);
        float ry = a.y + b.y + c.y + d.y + sl * bf2f(u.y);
        float rz = a.z + b.z + c.z + d.z + sl * bf2f(u.z);
        float rw = a.w + b.w + c.w + d.w + sl * bf2f(u.w);
        ushort4 o;
        o.x = f2bf(rx); o.y = f2bf(ry); o.z = f2bf(rz); o.w = f2bf(rw);
        xout[n * 64 + t] = o;
    }
}

// ------------- y[m][o] = bias[o] + sum_k A[m][k] W[o][k], bf16 MFMA, f32 out ------
// one wave computes a 16-node x 256-col tile; no LDS (A,B frags are 16B global loads)
__global__ __launch_bounds__(256) void k_gemm_mfma(const short* __restrict__ A,   // NN x 256 bf16
                                                   const short* __restrict__ B,   // 256 x 256 bf16 (W)
                                                   const float* __restrict__ bias,
                                                   float* __restrict__ y) {
    int wave = (blockIdx.x * 256 + threadIdx.x) >> 6;
    if (wave >= NN / 16) return;       // 1875 waves exactly
    int lane = threadIdx.x & 63;
    int m0 = wave * 16;
    int ml = lane & 15;                // row (A) / col-in-tile (B, D)
    int q  = lane >> 4;                // quad: A/B k = q*8+j, D row = q*4+r
    f32x4 acc[16];
    #pragma unroll
    for (int i = 0; i < 16; i++) acc[i] = (f32x4){0.f, 0.f, 0.f, 0.f};
    const short* arow = A + (m0 + ml) * NF + q * 8;
    #pragma unroll
    for (int ks = 0; ks < 8; ks++) {
        bf16x8 a = *(const bf16x8*)(arow + ks * 32);
        #pragma unroll
        for (int nt = 0; nt < 16; nt++) {
            bf16x8 b = *(const bf16x8*)(B + (nt * 16 + ml) * NF + ks * 32 + q * 8);
            acc[nt] = __builtin_amdgcn_mfma_f32_16x16x32_bf16(a, b, acc[nt], 0, 0, 0);
        }
    }
    #pragma unroll
    for (int nt = 0; nt < 16; nt++) {
        int col = nt * 16 + ml;
        float bb = bias[col];
        #pragma unroll
        for (int r = 0; r < 4; r++) {
            int row = m0 + q * 4 + r;
            y[row * NF + col] = acc[nt][r] + bb;
        }
    }
}

// ---------------- PReLU in place + per-feature sum/sumsq partials ----------------
__global__ __launch_bounds__(256) void k_prelu_stats(float* __restrict__ x,
                                                     const float* __restrict__ pw,
                                                     float* __restrict__ sums) {
    int t = threadIdx.x;               // feature
    float p = pw[t];
    float s = 0.f, s2 = 0.f;
    for (int n = blockIdx.x; n < NN; n += gridDim.x) {
        float v = x[n * NF + t];
        v = (v >= 0.f) ? v : p * v;
        x[n * NF + t] = v;
        s += v; s2 += v * v;
    }
    atomicAdd(&sums[t], s);
    atomicAdd(&sums[NF + t], s2);
}

// ---------------- finalize BN scale/shift ----------------
__global__ void k_finalize(const float* __restrict__ sums, const float* __restrict__ gamma,
                           const float* __restrict__ beta, float* __restrict__ ss) {
    int t = threadIdx.x;
    float mean = sums[t] / (float)NN;
    float var = sums[NF + t] / (float)NN - mean * mean;
    if (var < 0.f) var = 0.f;
    float istd = rsqrtf(var + EPS);
    float sc = gamma[t] * istd;
    ss[t] = sc;
    ss[NF + t] = beta[t] - mean * sc;
}

// ---------------- apply BN -> bf16 (feeds next prop chain) ----------------
__global__ void k_apply_h(const float4* __restrict__ y, const float* __restrict__ ss,
                          ushort4* __restrict__ xh) {
    int idx = blockIdx.x * 256 + threadIdx.x;          // float4 index
    if (idx >= NN * (NF / 4)) return;
    int f = (idx & 63) * 4;
    float4 v = y[idx];
    ushort4 o;
    o.x = f2bf(v.x * ss[f]     + ss[NF + f]);
    o.y = f2bf(v.y * ss[f + 1] + ss[NF + f + 1]);
    o.z = f2bf(v.z * ss[f + 2] + ss[NF + f + 2]);
    o.w = f2bf(v.w * ss[f + 3] + ss[NF + f + 3]);
    xh[idx] = o;
}

// ---------------- apply BN -> f32 output ----------------
__global__ void k_apply_out(const float4* __restrict__ y, const float* __restrict__ ss,
                            float4* __restrict__ out) {
    int idx = blockIdx.x * 256 + threadIdx.x;          // float4 index
    if (idx >= NN * (NF / 4)) return;
    int f = (idx & 63) * 4;
    float4 v = y[idx];
    float4 o;
    o.x = v.x * ss[f]     + ss[NF + f];
    o.y = v.y * ss[f + 1] + ss[NF + f + 1];
    o.z = v.z * ss[f + 2] + ss[NF + f + 2];
    o.w = v.w * ss[f + 3] + ss[NF + f + 3];
    out[idx] = o;
}

extern "C" void kernel_launch(void* const* d_in, const int* in_sizes, int n_in,
                              void* d_out, int out_size, void* d_ws, size_t ws_size,
                              hipStream_t stream) {
    const float* cell  = (const float*)d_in[0];
    const float* sub   = (const float*)d_in[1];
    const int*   ei    = (const int*)  d_in[2];
    const float* ew    = (const float*)d_in[3];
    const float* W1    = (const float*)d_in[4];
    const float* bias1 = (const float*)d_in[5];
    const float* W2    = (const float*)d_in[6];
    const float* bias2 = (const float*)d_in[7];
    const float* pw    = (const float*)d_in[8];
    const float* gamma = (const float*)d_in[9];
    const float* beta  = (const float*)d_in[10];
    float* out = (float*)d_out;        // reference output dtype is float32
    const int E = in_sizes[3];         // 960000 directed edges

    char* ws = (char*)d_ws;
    size_t off = 0;
    auto alloc = [&](size_t bytes) -> void* {
        void* p = ws + off;
        off = (off + bytes + 255) & ~((size_t)255);
        return p;
    };
    ushort4* xh0    = (ushort4*)alloc((size_t)NN * NF * 2);       // bf16 x ping
    ushort4* xh1    = (ushort4*)alloc((size_t)NN * NF * 2);       // bf16 x pong
    float*   yf     = (float*)  alloc((size_t)NN * NF * 4);       // f32 gemm out
    ushort4* W1h    = (ushort4*)alloc((size_t)NF * NF * 2);
    ushort4* W2h    = (ushort4*)alloc((size_t)NF * NF * 2);
    float*   deg    = (float*)  alloc((size_t)NN * 4);
    float*   dinv   = (float*)  alloc((size_t)NN * 4);
    int*     counts = (int*)    alloc((size_t)NN * 4);
    int*     col_ptr= (int*)    alloc((size_t)(NN + 1) * 4);
    int*     fill   = (int*)    alloc((size_t)NN * 4);
    int*     rs     = (int*)    alloc((size_t)E * 4);
    float*   ns     = (float*)  alloc((size_t)E * 4);
    float*   sums   = (float*)  alloc((size_t)2 * NF * 4);
    float*   ss     = (float*)  alloc((size_t)2 * NF * 4);

    const int gN  = (NN + 255) / 256;          // 118
    const int gE  = (E + 255) / 256;
    const int gV4 = (NN * NF / 4 + 255) / 256; // 7500
    const int gW4 = (NF * NF / 4 + 255) / 256; // 64
    const int gG  = ((NN / 16) * 64 + 255) / 256; // 469 blocks (1875 waves + pad)

    k_init<<<gN, 256, 0, stream>>>(deg, counts, fill, sums);
    k_concat_h<<<gV4, 256, 0, stream>>>((const float4*)cell, (const float4*)sub, xh0);
    k_cvtw<<<gW4, 256, 0, stream>>>((const float4*)W1, W1h);
    k_cvtw<<<gW4, 256, 0, stream>>>((const float4*)W2, W2h);
    k_pass1<<<gE, 256, 0, stream>>>(ei, ew, deg, counts, E);
    k_dinv<<<gN, 256, 0, stream>>>(deg, dinv);
    k_scan<<<1, 256, 0, stream>>>(counts, col_ptr);
    k_scatter<<<gE, 256, 0, stream>>>(ei, ew, dinv, col_ptr, fill, rs, ns, E);

    // ---------------- layer 1 ----------------
    k_prop<<<NN, 256, 0, stream>>>(xh0, xh1, col_ptr, rs, ns, dinv);
    k_prop<<<NN, 256, 0, stream>>>(xh1, xh0, col_ptr, rs, ns, dinv);
    k_prop<<<NN, 256, 0, stream>>>(xh0, xh1, col_ptr, rs, ns, dinv);
    k_gemm_mfma<<<gG, 256, 0, stream>>>((const short*)xh1, (const short*)W1h, bias1, yf);
    k_prelu_stats<<<256, 256, 0, stream>>>(yf, pw, sums);
    k_finalize<<<1, 256, 0, stream>>>(sums, gamma, beta, ss);
    k_apply_h<<<gV4, 256, 0, stream>>>((const float4*)yf, ss, xh0);

    // ---------------- layer 2 ----------------
    k_zero_stats<<<1, 512, 0, stream>>>(sums);
    k_prop<<<NN, 256, 0, stream>>>(xh0, xh1, col_ptr, rs, ns, dinv);
    k_prop<<<NN, 256, 0, stream>>>(xh1, xh0, col_ptr, rs, ns, dinv);
    k_prop<<<NN, 256, 0, stream>>>(xh0, xh1, col_ptr, rs, ns, dinv);
    k_gemm_mfma<<<gG, 256, 0, stream>>>((const short*)xh1, (const short*)W2h, bias2, yf);
    k_prelu_stats<<<256, 256, 0, stream>>>(yf, pw, sums);
    k_finalize<<<1, 256, 0, stream>>>(sums, gamma, beta, ss);
    k_apply_out<<<gV4, 256, 0, stream>>>((const float4*)yf, ss, (float4*)out);
}

// Round 6
// 918.754 us; speedup vs baseline: 1.5626x; 1.1654x over previous
//
#include <hip/hip_runtime.h>
#include <hip/hip_bf16.h>

constexpr int NN    = 30000;   // total nodes
constexpr int NCELL = 66;
constexpr int NF    = 256;     // features
constexpr float EPS = 1e-5f;

using bf16x8 = __attribute__((ext_vector_type(8))) short;   // 8 bf16 = 4 VGPRs
using f32x4  = __attribute__((ext_vector_type(4))) float;

__device__ __forceinline__ float bf2f(unsigned short u) {
    return __uint_as_float(((unsigned)u) << 16);
}
__device__ __forceinline__ unsigned short f2bf(float f) {
    __hip_bfloat16 h = __float2bfloat16(f);   // RNE
    return *reinterpret_cast<unsigned short*>(&h);
}
// accumulate 8 bf16 features packed in a float4 (bit halves), f32 math
__device__ __forceinline__ void acc8(float* acc, float4 u, float w) {
    unsigned a = __float_as_uint(u.x), b = __float_as_uint(u.y);
    unsigned c = __float_as_uint(u.z), d = __float_as_uint(u.w);
    acc[0] += w * __uint_as_float(a << 16);
    acc[1] += w * __uint_as_float(a & 0xffff0000u);
    acc[2] += w * __uint_as_float(b << 16);
    acc[3] += w * __uint_as_float(b & 0xffff0000u);
    acc[4] += w * __uint_as_float(c << 16);
    acc[5] += w * __uint_as_float(c & 0xffff0000u);
    acc[6] += w * __uint_as_float(d << 16);
    acc[7] += w * __uint_as_float(d & 0xffff0000u);
}

// ---------------- init: deg=1 (self loop), counts/fill/sums = 0 ----------------
__global__ void k_init(float* deg, int* counts, int* fill, float* sums) {
    int i = blockIdx.x * 256 + threadIdx.x;
    if (i < NN) { deg[i] = 1.0f; counts[i] = 0; fill[i] = 0; }
    if (i < 2 * NF) sums[i] = 0.0f;
}

__global__ void k_zero_stats(float* sums) {
    int i = threadIdx.x;
    if (i < 2 * NF) sums[i] = 0.0f;
}

// ---------------- concat (cell ++ sub) f32 -> bf16 ----------------
__global__ void k_concat_h(const float4* __restrict__ cell, const float4* __restrict__ sub,
                           ushort4* __restrict__ xh) {
    int idx = blockIdx.x * 256 + threadIdx.x;          // float4 index
    if (idx >= NN * (NF / 4)) return;
    const int CELL4 = NCELL * (NF / 4);
    float4 v = (idx < CELL4) ? cell[idx] : sub[idx - CELL4];
    ushort4 o;
    o.x = f2bf(v.x); o.y = f2bf(v.y); o.z = f2bf(v.z); o.w = f2bf(v.w);
    xh[idx] = o;
}

// ---------------- convert W (f32, o-major k-contig) -> bf16 ----------------
__global__ void k_cvtw(const float4* __restrict__ W, ushort4* __restrict__ Wh) {
    int idx = blockIdx.x * 256 + threadIdx.x;
    if (idx >= NF * NF / 4) return;
    float4 v = W[idx];
    ushort4 o;
    o.x = f2bf(v.x); o.y = f2bf(v.y); o.z = f2bf(v.z); o.w = f2bf(v.w);
    Wh[idx] = o;
}

// ---------------- degree + per-col edge counts ----------------
__global__ void k_pass1(const int* __restrict__ ei, const float* __restrict__ ew,
                        float* deg, int* counts, int E) {
    int e = blockIdx.x * 256 + threadIdx.x;
    if (e >= E) return;
    int col = ei[E + e];
    atomicAdd(&deg[col], ew[e]);
    atomicAdd(&counts[col], 1);
}

__global__ void k_dinv(const float* __restrict__ deg, float* __restrict__ dinv) {
    int i = blockIdx.x * 256 + threadIdx.x;
    if (i < NN) dinv[i] = rsqrtf(deg[i]);   // deg >= 1 always (self loop)
}

// ---------------- exclusive prefix sum of counts -> col_ptr (single block) --------
__global__ void k_scan(const int* __restrict__ counts, int* __restrict__ col_ptr) {
    __shared__ int part[256];
    __shared__ int pref[257];
    int t = threadIdx.x;
    const int CH = (NN + 255) / 256;   // 118
    int beg = t * CH;
    int end = beg + CH; if (end > NN) end = NN;
    int s = 0;
    for (int i = beg; i < end; i++) s += counts[i];
    part[t] = s;
    __syncthreads();
    if (t == 0) {
        int r = 0;
        for (int i = 0; i < 256; i++) { pref[i] = r; r += part[i]; }
        pref[256] = r;
    }
    __syncthreads();
    int run = pref[t];
    for (int i = beg; i < end; i++) { col_ptr[i] = run; run += counts[i]; }
    if (t == 255) col_ptr[NN] = pref[256];
}

// ---------------- scatter edges into CSR (sorted by col), compute norm ------------
__global__ void k_scatter(const int* __restrict__ ei, const float* __restrict__ ew,
                          const float* __restrict__ dinv, const int* __restrict__ col_ptr,
                          int* fill, int* __restrict__ rs, float* __restrict__ ns, int E) {
    int e = blockIdx.x * 256 + threadIdx.x;
    if (e >= E) return;
    int row = ei[e];
    int col = ei[E + e];
    float nrm = dinv[row] * ew[e] * dinv[col];
    int pos = col_ptr[col] + atomicAdd(&fill[col], 1);
    rs[pos] = row;
    ns[pos] = nrm;
}

// ------------- one hop: y = A_hat x, bf16 in/out, f32 accum ------------------------
// 1 wave per node; 32 lanes span the 512B row (16B/lane); halves process even/odd
// edges => 2 edges per load instr; pair-loop unrolled x4 => 8 edges in flight.
__global__ __launch_bounds__(256) void k_prop(const ushort* __restrict__ xin,
                                              ushort* __restrict__ xout,
                                              const int* __restrict__ col_ptr,
                                              const int* __restrict__ rs,
                                              const float* __restrict__ ns,
                                              const float* __restrict__ dinv) {
    int n = blockIdx.x * 4 + (threadIdx.x >> 6);
    int lane = threadIdx.x & 63;
    int half = lane >> 5;              // 0: even edges, 1: odd edges
    int fb = lane & 31;                // features fb*8 .. fb*8+7
    const float4* xrow = (const float4*)xin;    // row r = x4[r*32 + fb]
    int beg = col_ptr[n], end = col_ptr[n + 1];
    int cnt = end - beg;
    float acc[8];
    #pragma unroll
    for (int i = 0; i < 8; i++) acc[i] = 0.f;
    int steps = cnt >> 1;
    int it = 0;
    int e = beg + half;
    for (; it + 4 <= steps; it += 4, e += 8) {
        int   s0 = rs[e],     s1 = rs[e + 2], s2 = rs[e + 4], s3 = rs[e + 6];
        float w0 = ns[e],     w1 = ns[e + 2], w2 = ns[e + 4], w3 = ns[e + 6];
        float4 u0 = xrow[s0 * 32 + fb];
        float4 u1 = xrow[s1 * 32 + fb];
        float4 u2 = xrow[s2 * 32 + fb];
        float4 u3 = xrow[s3 * 32 + fb];
        acc8(acc, u0, w0); acc8(acc, u1, w1); acc8(acc, u2, w2); acc8(acc, u3, w3);
    }
    for (; it < steps; ++it, e += 2) {
        int s0 = rs[e]; float w0 = ns[e];
        float4 u0 = xrow[s0 * 32 + fb];
        acc8(acc, u0, w0);
    }
    if ((cnt & 1) && half == 0) {          // odd remainder edge
        int el = beg + cnt - 1;
        float4 u0 = xrow[rs[el] * 32 + fb];
        acc8(acc, u0, ns[el]);
    }
    #pragma unroll
    for (int i = 0; i < 8; i++) acc[i] += __shfl_xor(acc[i], 32);
    if (half == 0) {
        float dn = dinv[n];
        float4 u = xrow[n * 32 + fb];
        acc8(acc, u, dn * dn);             // self loop
        unsigned p0 = ((unsigned)f2bf(acc[1]) << 16) | f2bf(acc[0]);
        unsigned p1 = ((unsigned)f2bf(acc[3]) << 16) | f2bf(acc[2]);
        unsigned p2 = ((unsigned)f2bf(acc[5]) << 16) | f2bf(acc[4]);
        unsigned p3 = ((unsigned)f2bf(acc[7]) << 16) | f2bf(acc[6]);
        float4 o;
        o.x = __uint_as_float(p0); o.y = __uint_as_float(p1);
        o.z = __uint_as_float(p2); o.w = __uint_as_float(p3);
        ((float4*)xout)[n * 32 + fb] = o;
    }
}

// ------- y[m][o] = PReLU(bias[o] + sum_k A[m][k] W[o][k]) -> bf16, + BN stats -----
// one wave per 16-node x 256-col tile; stats reduced cross-lane, 1 atomic/col/wave
__global__ __launch_bounds__(256) void k_gemm_fused(const short* __restrict__ A,  // NN x 256 bf16
                                                    const short* __restrict__ B,  // 256 x 256 bf16 (W)
                                                    const float* __restrict__ bias,
                                                    const float* __restrict__ pw,
                                                    ushort* __restrict__ y,       // NN x 256 bf16
                                                    float* __restrict__ sums) {
    int wave = (blockIdx.x * 256 + threadIdx.x) >> 6;
    if (wave >= NN / 16) return;       // 1875 waves
    int lane = threadIdx.x & 63;
    int m0 = wave * 16;
    int ml = lane & 15;                // row (A) / col-in-tile (B, D)
    int q  = lane >> 4;                // quad: A/B k = q*8+j, D row = q*4+r
    f32x4 acc[16];
    #pragma unroll
    for (int i = 0; i < 16; i++) acc[i] = (f32x4){0.f, 0.f, 0.f, 0.f};
    const short* arow = A + (m0 + ml) * NF + q * 8;
    #pragma unroll
    for (int ks = 0; ks < 8; ks++) {
        bf16x8 a = *(const bf16x8*)(arow + ks * 32);
        #pragma unroll
        for (int nt = 0; nt < 16; nt++) {
            bf16x8 b = *(const bf16x8*)(B + (nt * 16 + ml) * NF + ks * 32 + q * 8);
            acc[nt] = __builtin_amdgcn_mfma_f32_16x16x32_bf16(a, b, acc[nt], 0, 0, 0);
        }
    }
    #pragma unroll
    for (int nt = 0; nt < 16; nt++) {
        int col = nt * 16 + ml;
        float bb = bias[col];
        float pc = pw[col];
        float s = 0.f, s2 = 0.f;
        #pragma unroll
        for (int r = 0; r < 4; r++) {
            float v = acc[nt][r] + bb;
            v = (v >= 0.f) ? v : pc * v;
            s += v; s2 += v * v;
            y[(m0 + q * 4 + r) * NF + col] = f2bf(v);
        }
        s  += __shfl_xor(s, 16);  s  += __shfl_xor(s, 32);
        s2 += __shfl_xor(s2, 16); s2 += __shfl_xor(s2, 32);
        if (lane < 16) {
            atomicAdd(&sums[col], s);
            atomicAdd(&sums[NF + col], s2);
        }
    }
}

// ---------------- finalize BN scale/shift ----------------
__global__ void k_finalize(const float* __restrict__ sums, const float* __restrict__ gamma,
                           const float* __restrict__ beta, float* __restrict__ ss) {
    int t = threadIdx.x;
    float mean = sums[t] / (float)NN;
    float var = sums[NF + t] / (float)NN - mean * mean;
    if (var < 0.f) var = 0.f;
    float istd = rsqrtf(var + EPS);
    float sc = gamma[t] * istd;
    ss[t] = sc;
    ss[NF + t] = beta[t] - mean * sc;
}

// ---------------- apply BN: bf16 y -> bf16 x (feeds next prop chain) ----------------
__global__ void k_apply_h(const ushort4* __restrict__ y, const float* __restrict__ ss,
                          ushort4* __restrict__ xh) {
    int idx = blockIdx.x * 256 + threadIdx.x;          // ushort4 index
    if (idx >= NN * (NF / 4)) return;
    int f = (idx & 63) * 4;
    ushort4 u = y[idx];
    ushort4 o;
    o.x = f2bf(bf2f(u.x) * ss[f]     + ss[NF + f]);
    o.y = f2bf(bf2f(u.y) * ss[f + 1] + ss[NF + f + 1]);
    o.z = f2bf(bf2f(u.z) * ss[f + 2] + ss[NF + f + 2]);
    o.w = f2bf(bf2f(u.w) * ss[f + 3] + ss[NF + f + 3]);
    xh[idx] = o;
}

// ---------------- apply BN: bf16 y -> f32 output ----------------
__global__ void k_apply_out(const ushort4* __restrict__ y, const float* __restrict__ ss,
                            float4* __restrict__ out) {
    int idx = blockIdx.x * 256 + threadIdx.x;          // ushort4 index
    if (idx >= NN * (NF / 4)) return;
    int f = (idx & 63) * 4;
    ushort4 u = y[idx];
    float4 o;
    o.x = bf2f(u.x) * ss[f]     + ss[NF + f];
    o.y = bf2f(u.y) * ss[f + 1] + ss[NF + f + 1];
    o.z = bf2f(u.z) * ss[f + 2] + ss[NF + f + 2];
    o.w = bf2f(u.w) * ss[f + 3] + ss[NF + f + 3];
    out[idx] = o;
}

extern "C" void kernel_launch(void* const* d_in, const int* in_sizes, int n_in,
                              void* d_out, int out_size, void* d_ws, size_t ws_size,
                              hipStream_t stream) {
    const float* cell  = (const float*)d_in[0];
    const float* sub   = (const float*)d_in[1];
    const int*   ei    = (const int*)  d_in[2];
    const float* ew    = (const float*)d_in[3];
    const float* W1    = (const float*)d_in[4];
    const float* bias1 = (const float*)d_in[5];
    const float* W2    = (const float*)d_in[6];
    const float* bias2 = (const float*)d_in[7];
    const float* pw    = (const float*)d_in[8];
    const float* gamma = (const float*)d_in[9];
    const float* beta  = (const float*)d_in[10];
    float* out = (float*)d_out;        // reference output dtype is float32
    const int E = in_sizes[3];         // 960000 directed edges

    char* ws = (char*)d_ws;
    size_t off = 0;
    auto alloc = [&](size_t bytes) -> void* {
        void* p = ws + off;
        off = (off + bytes + 255) & ~((size_t)255);
        return p;
    };
    ushort* xh0    = (ushort*)alloc((size_t)NN * NF * 2);       // bf16 x ping
    ushort* xh1    = (ushort*)alloc((size_t)NN * NF * 2);       // bf16 x pong
    ushort* yh     = (ushort*)alloc((size_t)NN * NF * 2);       // bf16 prelu'd gemm out
    ushort* W1h    = (ushort*)alloc((size_t)NF * NF * 2);
    ushort* W2h    = (ushort*)alloc((size_t)NF * NF * 2);
    float*  deg    = (float*) alloc((size_t)NN * 4);
    float*  dinv   = (float*) alloc((size_t)NN * 4);
    int*    counts = (int*)   alloc((size_t)NN * 4);
    int*    col_ptr= (int*)   alloc((size_t)(NN + 1) * 4);
    int*    fill   = (int*)   alloc((size_t)NN * 4);
    int*    rs     = (int*)   alloc((size_t)E * 4);
    float*  ns     = (float*) alloc((size_t)E * 4);
    float*  sums   = (float*) alloc((size_t)2 * NF * 4);
    float*  ss     = (float*) alloc((size_t)2 * NF * 4);

    const int gN  = (NN + 255) / 256;             // 118
    const int gE  = (E + 255) / 256;
    const int gV4 = (NN * NF / 4 + 255) / 256;    // 7500
    const int gW4 = (NF * NF / 4 + 255) / 256;    // 64
    const int gP  = NN / 4;                       // 7500 blocks, 1 wave/node
    const int gG  = ((NN / 16) * 64 + 255) / 256; // 469 blocks (1875 waves + pad)

    k_init<<<gN, 256, 0, stream>>>(deg, counts, fill, sums);
    k_concat_h<<<gV4, 256, 0, stream>>>((const float4*)cell, (const float4*)sub, (ushort4*)xh0);
    k_cvtw<<<gW4, 256, 0, stream>>>((const float4*)W1, (ushort4*)W1h);
    k_cvtw<<<gW4, 256, 0, stream>>>((const float4*)W2, (ushort4*)W2h);
    k_pass1<<<gE, 256, 0, stream>>>(ei, ew, deg, counts, E);
    k_dinv<<<gN, 256, 0, stream>>>(deg, dinv);
    k_scan<<<1, 256, 0, stream>>>(counts, col_ptr);
    k_scatter<<<gE, 256, 0, stream>>>(ei, ew, dinv, col_ptr, fill, rs, ns, E);

    // ---------------- layer 1 ----------------
    k_prop<<<gP, 256, 0, stream>>>(xh0, xh1, col_ptr, rs, ns, dinv);
    k_prop<<<gP, 256, 0, stream>>>(xh1, xh0, col_ptr, rs, ns, dinv);
    k_prop<<<gP, 256, 0, stream>>>(xh0, xh1, col_ptr, rs, ns, dinv);
    k_gemm_fused<<<gG, 256, 0, stream>>>((const short*)xh1, (const short*)W1h, bias1, pw, yh, sums);
    k_finalize<<<1, 256, 0, stream>>>(sums, gamma, beta, ss);
    k_apply_h<<<gV4, 256, 0, stream>>>((const ushort4*)yh, ss, (ushort4*)xh0);
    k_zero_stats<<<1, 512, 0, stream>>>(sums);

    // ---------------- layer 2 ----------------
    k_prop<<<gP, 256, 0, stream>>>(xh0, xh1, col_ptr, rs, ns, dinv);
    k_prop<<<gP, 256, 0, stream>>>(xh1, xh0, col_ptr, rs, ns, dinv);
    k_prop<<<gP, 256, 0, stream>>>(xh0, xh1, col_ptr, rs, ns, dinv);
    k_gemm_fused<<<gG, 256, 0, stream>>>((const short*)xh1, (const short*)W2h, bias2, pw, yh, sums);
    k_finalize<<<1, 256, 0, stream>>>(sums, gamma, beta, ss);
    k_apply_out<<<gV4, 256, 0, stream>>>((const ushort4*)yh, ss, (float4*)out);
}

// Round 9
// 786.042 us; speedup vs baseline: 1.8264x; 1.1688x over previous
//
#include <hip/hip_runtime.h>
#include <hip/hip_bf16.h>

constexpr int NN    = 30000;   // total nodes
constexpr int NCELL = 66;
constexpr int NF    = 256;     // features
constexpr float EPS = 1e-5f;

using bf16x8 = __attribute__((ext_vector_type(8))) short;   // 8 bf16 = 4 VGPRs
using f32x4  = __attribute__((ext_vector_type(4))) float;

__device__ __forceinline__ float bf2f(unsigned short u) {
    return __uint_as_float(((unsigned)u) << 16);
}
__device__ __forceinline__ unsigned short f2bf(float f) {
    __hip_bfloat16 h = __float2bfloat16(f);   // RNE
    return *reinterpret_cast<unsigned short*>(&h);
}
// accumulate 8 bf16 features packed in a float4 (bit halves), f32 math
__device__ __forceinline__ void acc8(float* acc, float4 u, float w) {
    unsigned a = __float_as_uint(u.x), b = __float_as_uint(u.y);
    unsigned c = __float_as_uint(u.z), d = __float_as_uint(u.w);
    acc[0] += w * __uint_as_float(a << 16);
    acc[1] += w * __uint_as_float(a & 0xffff0000u);
    acc[2] += w * __uint_as_float(b << 16);
    acc[3] += w * __uint_as_float(b & 0xffff0000u);
    acc[4] += w * __uint_as_float(c << 16);
    acc[5] += w * __uint_as_float(c & 0xffff0000u);
    acc[6] += w * __uint_as_float(d << 16);
    acc[7] += w * __uint_as_float(d & 0xffff0000u);
}

// ---------------- init: deg=1 (self loop), counts/fill/sums = 0 ----------------
__global__ void k_init(float* deg, int* counts, int* fill, float* sums) {
    int i = blockIdx.x * 256 + threadIdx.x;
    if (i < NN) { deg[i] = 1.0f; counts[i] = 0; fill[i] = 0; }
    if (i < 2 * NF) sums[i] = 0.0f;
}

__global__ void k_zero_stats(float* sums) {
    int i = threadIdx.x;
    if (i < 2 * NF) sums[i] = 0.0f;
}

// ---------------- concat (cell ++ sub) f32 -> bf16 ----------------
__global__ void k_concat_h(const float4* __restrict__ cell, const float4* __restrict__ sub,
                           ushort4* __restrict__ xh) {
    int idx = blockIdx.x * 256 + threadIdx.x;          // float4 index
    if (idx >= NN * (NF / 4)) return;
    const int CELL4 = NCELL * (NF / 4);
    float4 v = (idx < CELL4) ? cell[idx] : sub[idx - CELL4];
    ushort4 o;
    o.x = f2bf(v.x); o.y = f2bf(v.y); o.z = f2bf(v.z); o.w = f2bf(v.w);
    xh[idx] = o;
}

// ---------------- convert W (f32, o-major k-contig) -> bf16 ----------------
__global__ void k_cvtw(const float4* __restrict__ W, ushort4* __restrict__ Wh) {
    int idx = blockIdx.x * 256 + threadIdx.x;
    if (idx >= NF * NF / 4) return;
    float4 v = W[idx];
    ushort4 o;
    o.x = f2bf(v.x); o.y = f2bf(v.y); o.z = f2bf(v.z); o.w = f2bf(v.w);
    Wh[idx] = o;
}

// ---------------- degree + per-col edge counts ----------------
__global__ void k_pass1(const int* __restrict__ ei, const float* __restrict__ ew,
                        float* deg, int* counts, int E) {
    int e = blockIdx.x * 256 + threadIdx.x;
    if (e >= E) return;
    int col = ei[E + e];
    atomicAdd(&deg[col], ew[e]);
    atomicAdd(&counts[col], 1);
}

__global__ void k_dinv(const float* __restrict__ deg, float* __restrict__ dinv) {
    int i = blockIdx.x * 256 + threadIdx.x;
    if (i < NN) dinv[i] = rsqrtf(deg[i]);   // deg >= 1 always (self loop)
}

// ---------------- exclusive prefix sum of counts -> col_ptr (single block) --------
__global__ void k_scan(const int* __restrict__ counts, int* __restrict__ col_ptr) {
    __shared__ int part[256];
    __shared__ int pref[257];
    int t = threadIdx.x;
    const int CH = (NN + 255) / 256;   // 118
    int beg = t * CH;
    int end = beg + CH; if (end > NN) end = NN;
    int s = 0;
    for (int i = beg; i < end; i++) s += counts[i];
    part[t] = s;
    __syncthreads();
    if (t == 0) {
        int r = 0;
        for (int i = 0; i < 256; i++) { pref[i] = r; r += part[i]; }
        pref[256] = r;
    }
    __syncthreads();
    int run = pref[t];
    for (int i = beg; i < end; i++) { col_ptr[i] = run; run += counts[i]; }
    if (t == 255) col_ptr[NN] = pref[256];
}

// ---------------- scatter edges into CSR (sorted by col), compute norm ------------
__global__ void k_scatter(const int* __restrict__ ei, const float* __restrict__ ew,
                          const float* __restrict__ dinv, const int* __restrict__ col_ptr,
                          int* fill, int* __restrict__ rs, float* __restrict__ ns, int E) {
    int e = blockIdx.x * 256 + threadIdx.x;
    if (e >= E) return;
    int row = ei[e];
    int col = ei[E + e];
    float nrm = dinv[row] * ew[e] * dinv[col];
    int pos = col_ptr[col] + atomicAdd(&fill[col], 1);
    rs[pos] = row;
    ns[pos] = nrm;
}

// ------------- one hop: y = A_hat x, bf16 in/out, f32 accum ------------------------
// 1 wave per node; 32 lanes span the 512B row (16B/lane); halves process even/odd
// edges => 2 edges per load instr; pair-loop unrolled x4 => 8 edges in flight.
__global__ __launch_bounds__(256) void k_prop(const ushort* __restrict__ xin,
                                              ushort* __restrict__ xout,
                                              const int* __restrict__ col_ptr,
                                              const int* __restrict__ rs,
                                              const float* __restrict__ ns,
                                              const float* __restrict__ dinv) {
    int n = blockIdx.x * 4 + (threadIdx.x >> 6);
    int lane = threadIdx.x & 63;
    int half = lane >> 5;              // 0: even edges, 1: odd edges
    int fb = lane & 31;                // features fb*8 .. fb*8+7
    const float4* xrow = (const float4*)xin;    // row r = x4[r*32 + fb]
    int beg = col_ptr[n], end = col_ptr[n + 1];
    int cnt = end - beg;
    float acc[8];
    #pragma unroll
    for (int i = 0; i < 8; i++) acc[i] = 0.f;
    int steps = cnt >> 1;
    int it = 0;
    int e = beg + half;
    for (; it + 4 <= steps; it += 4, e += 8) {
        int   s0 = rs[e],     s1 = rs[e + 2], s2 = rs[e + 4], s3 = rs[e + 6];
        float w0 = ns[e],     w1 = ns[e + 2], w2 = ns[e + 4], w3 = ns[e + 6];
        float4 u0 = xrow[s0 * 32 + fb];
        float4 u1 = xrow[s1 * 32 + fb];
        float4 u2 = xrow[s2 * 32 + fb];
        float4 u3 = xrow[s3 * 32 + fb];
        acc8(acc, u0, w0); acc8(acc, u1, w1); acc8(acc, u2, w2); acc8(acc, u3, w3);
    }
    for (; it < steps; ++it, e += 2) {
        int s0 = rs[e]; float w0 = ns[e];
        float4 u0 = xrow[s0 * 32 + fb];
        acc8(acc, u0, w0);
    }
    if ((cnt & 1) && half == 0) {          // odd remainder edge
        int el = beg + cnt - 1;
        float4 u0 = xrow[rs[el] * 32 + fb];
        acc8(acc, u0, ns[el]);
    }
    #pragma unroll
    for (int i = 0; i < 8; i++) acc[i] += __shfl_xor(acc[i], 32);
    if (half == 0) {
        float dn = dinv[n];
        float4 u = xrow[n * 32 + fb];
        acc8(acc, u, dn * dn);             // self loop
        unsigned p0 = ((unsigned)f2bf(acc[1]) << 16) | f2bf(acc[0]);
        unsigned p1 = ((unsigned)f2bf(acc[3]) << 16) | f2bf(acc[2]);
        unsigned p2 = ((unsigned)f2bf(acc[5]) << 16) | f2bf(acc[4]);
        unsigned p3 = ((unsigned)f2bf(acc[7]) << 16) | f2bf(acc[6]);
        float4 o;
        o.x = __uint_as_float(p0); o.y = __uint_as_float(p1);
        o.z = __uint_as_float(p2); o.w = __uint_as_float(p3);
        ((float4*)xout)[n * 32 + fb] = o;
    }
}

// ------- y[m][o] = PReLU(bias[o] + sum_k A[m][k] W[o][k]) -> f32, + BN stats ------
// r6-verified wave mapping: wave = 16 rows x full 256 cols (acc[16]). New: stats go
// through LDS block-reduce (4 waves) -> 512 atomics/block instead of per-wave
// atomics (960k -> 240k). Invalid pad wave is guarded (no early return: barrier!).
__global__ __launch_bounds__(256) void k_gemm_fused(const short* __restrict__ A,  // NN x 256 bf16
                                                    const short* __restrict__ B,  // 256 x 256 bf16 (W)
                                                    const float* __restrict__ bias,
                                                    const float* __restrict__ pw,
                                                    float* __restrict__ y,        // NN x 256 f32
                                                    float* __restrict__ sums) {
    constexpr int RT = NN / 16;        // 1875 row tiles
    int w    = threadIdx.x >> 6;       // wave in block
    int lane = threadIdx.x & 63;
    int rt   = blockIdx.x * 4 + w;     // r6 mapping: 4 row tiles per block
    int ml   = lane & 15;              // row in tile (A) / col in 16-tile (B, D)
    int q    = lane >> 4;              // quad: A/B k = q*8+j, D row = q*4+r
    bool valid = rt < RT;
    __shared__ float red[2][4][NF];    // [s|s2][wave][col] = 8 KB
    f32x4 acc[16];
    #pragma unroll
    for (int i = 0; i < 16; i++) acc[i] = (f32x4){0.f, 0.f, 0.f, 0.f};
    if (valid) {
        const short* arow = A + (rt * 16 + ml) * NF + q * 8;
        #pragma unroll
        for (int ks = 0; ks < 8; ks++) {
            bf16x8 a = *(const bf16x8*)(arow + ks * 32);
            #pragma unroll
            for (int nt = 0; nt < 16; nt++) {
                bf16x8 b = *(const bf16x8*)(B + (nt * 16 + ml) * NF + ks * 32 + q * 8);
                acc[nt] = __builtin_amdgcn_mfma_f32_16x16x32_bf16(a, b, acc[nt], 0, 0, 0);
            }
        }
    }
    #pragma unroll
    for (int nt = 0; nt < 16; nt++) {
        int col = nt * 16 + ml;
        float s = 0.f, s2 = 0.f;
        if (valid) {
            float bb = bias[col];
            float pc = pw[col];
            #pragma unroll
            for (int r = 0; r < 4; r++) {
                float v = acc[nt][r] + bb;
                v = (v >= 0.f) ? v : pc * v;
                s += v; s2 += v * v;
                y[(rt * 16 + q * 4 + r) * NF + col] = v;
            }
        }
        s  += __shfl_xor(s, 16);  s  += __shfl_xor(s, 32);
        s2 += __shfl_xor(s2, 16); s2 += __shfl_xor(s2, 32);
        if (lane < 16) { red[0][w][col] = s; red[1][w][col] = s2; }
    }
    __syncthreads();
    int t = threadIdx.x;               // t = col, all 256 threads
    float v0 = red[0][0][t] + red[0][1][t] + red[0][2][t] + red[0][3][t];
    float v1 = red[1][0][t] + red[1][1][t] + red[1][2][t] + red[1][3][t];
    atomicAdd(&sums[t], v0);
    atomicAdd(&sums[NF + t], v1);
}

// ---------------- finalize BN scale/shift ----------------
__global__ void k_finalize(const float* __restrict__ sums, const float* __restrict__ gamma,
                           const float* __restrict__ beta, float* __restrict__ ss) {
    int t = threadIdx.x;
    float mean = sums[t] / (float)NN;
    float var = sums[NF + t] / (float)NN - mean * mean;
    if (var < 0.f) var = 0.f;
    float istd = rsqrtf(var + EPS);
    float sc = gamma[t] * istd;
    ss[t] = sc;
    ss[NF + t] = beta[t] - mean * sc;
}

// ---------------- apply BN: f32 y -> bf16 x (feeds next prop chain) ----------------
__global__ void k_apply_h(const float4* __restrict__ y, const float* __restrict__ ss,
                          ushort4* __restrict__ xh) {
    int idx = blockIdx.x * 256 + threadIdx.x;          // float4 index
    if (idx >= NN * (NF / 4)) return;
    int f = (idx & 63) * 4;
    float4 v = y[idx];
    ushort4 o;
    o.x = f2bf(v.x * ss[f]     + ss[NF + f]);
    o.y = f2bf(v.y * ss[f + 1] + ss[NF + f + 1]);
    o.z = f2bf(v.z * ss[f + 2] + ss[NF + f + 2]);
    o.w = f2bf(v.w * ss[f + 3] + ss[NF + f + 3]);
    xh[idx] = o;
}

// ---------------- apply BN: f32 y -> f32 output ----------------
__global__ void k_apply_out(const float4* __restrict__ y, const float* __restrict__ ss,
                            float4* __restrict__ out) {
    int idx = blockIdx.x * 256 + threadIdx.x;          // float4 index
    if (idx >= NN * (NF / 4)) return;
    int f = (idx & 63) * 4;
    float4 v = y[idx];
    float4 o;
    o.x = v.x * ss[f]     + ss[NF + f];
    o.y = v.y * ss[f + 1] + ss[NF + f + 1];
    o.z = v.z * ss[f + 2] + ss[NF + f + 2];
    o.w = v.w * ss[f + 3] + ss[NF + f + 3];
    out[idx] = o;
}

extern "C" void kernel_launch(void* const* d_in, const int* in_sizes, int n_in,
                              void* d_out, int out_size, void* d_ws, size_t ws_size,
                              hipStream_t stream) {
    const float* cell  = (const float*)d_in[0];
    const float* sub   = (const float*)d_in[1];
    const int*   ei    = (const int*)  d_in[2];
    const float* ew    = (const float*)d_in[3];
    const float* W1    = (const float*)d_in[4];
    const float* bias1 = (const float*)d_in[5];
    const float* W2    = (const float*)d_in[6];
    const float* bias2 = (const float*)d_in[7];
    const float* pw    = (const float*)d_in[8];
    const float* gamma = (const float*)d_in[9];
    const float* beta  = (const float*)d_in[10];
    float* out = (float*)d_out;        // reference output dtype is float32
    const int E = in_sizes[3];         // 960000 directed edges

    char* ws = (char*)d_ws;
    size_t off = 0;
    auto alloc = [&](size_t bytes) -> void* {
        void* p = ws + off;
        off = (off + bytes + 255) & ~((size_t)255);
        return p;
    };
    ushort* xh0    = (ushort*)alloc((size_t)NN * NF * 2);       // bf16 x ping
    ushort* xh1    = (ushort*)alloc((size_t)NN * NF * 2);       // bf16 x pong
    float*  yf     = (float*) alloc((size_t)NN * NF * 4);       // f32 prelu'd gemm out
    ushort* W1h    = (ushort*)alloc((size_t)NF * NF * 2);
    ushort* W2h    = (ushort*)alloc((size_t)NF * NF * 2);
    float*  deg    = (float*) alloc((size_t)NN * 4);
    float*  dinv   = (float*) alloc((size_t)NN * 4);
    int*    counts = (int*)   alloc((size_t)NN * 4);
    int*    col_ptr= (int*)   alloc((size_t)(NN + 1) * 4);
    int*    fill   = (int*)   alloc((size_t)NN * 4);
    int*    rs     = (int*)   alloc((size_t)E * 4);
    float*  ns     = (float*) alloc((size_t)E * 4);
    float*  sums   = (float*) alloc((size_t)2 * NF * 4);
    float*  ss     = (float*) alloc((size_t)2 * NF * 4);

    const int gN  = (NN + 255) / 256;             // 118
    const int gE  = (E + 255) / 256;
    const int gV4 = (NN * NF / 4 + 255) / 256;    // 7500
    const int gW4 = (NF * NF / 4 + 255) / 256;    // 64
    const int gP  = NN / 4;                       // 7500 blocks, 1 wave/node
    const int gG  = (NN / 16 + 3) / 4;            // 469 blocks x 4 waves (r6 grid)

    k_init<<<gN, 256, 0, stream>>>(deg, counts, fill, sums);
    k_concat_h<<<gV4, 256, 0, stream>>>((const float4*)cell, (const float4*)sub, (ushort4*)xh0);
    k_cvtw<<<gW4, 256, 0, stream>>>((const float4*)W1, (ushort4*)W1h);
    k_cvtw<<<gW4, 256, 0, stream>>>((const float4*)W2, (ushort4*)W2h);
    k_pass1<<<gE, 256, 0, stream>>>(ei, ew, deg, counts, E);
    k_dinv<<<gN, 256, 0, stream>>>(deg, dinv);
    k_scan<<<1, 256, 0, stream>>>(counts, col_ptr);
    k_scatter<<<gE, 256, 0, stream>>>(ei, ew, dinv, col_ptr, fill, rs, ns, E);

    // ---------------- layer 1 ----------------
    k_prop<<<gP, 256, 0, stream>>>(xh0, xh1, col_ptr, rs, ns, dinv);
    k_prop<<<gP, 256, 0, stream>>>(xh1, xh0, col_ptr, rs, ns, dinv);
    k_prop<<<gP, 256, 0, stream>>>(xh0, xh1, col_ptr, rs, ns, dinv);
    k_gemm_fused<<<gG, 256, 0, stream>>>((const short*)xh1, (const short*)W1h, bias1, pw, yf, sums);
    k_finalize<<<1, 256, 0, stream>>>(sums, gamma, beta, ss);
    k_apply_h<<<gV4, 256, 0, stream>>>((const float4*)yf, ss, (ushort4*)xh0);
    k_zero_stats<<<1, 512, 0, stream>>>(sums);

    // ---------------- layer 2 ----------------
    k_prop<<<gP, 256, 0, stream>>>(xh0, xh1, col_ptr, rs, ns, dinv);
    k_prop<<<gP, 256, 0, stream>>>(xh1, xh0, col_ptr, rs, ns, dinv);
    k_prop<<<gP, 256, 0, stream>>>(xh0, xh1, col_ptr, rs, ns, dinv);
    k_gemm_fused<<<gG, 256, 0, stream>>>((const short*)xh1, (const short*)W2h, bias2, pw, yf, sums);
    k_finalize<<<1, 256, 0, stream>>>(sums, gamma, beta, ss);
    k_apply_out<<<gV4, 256, 0, stream>>>((const float4*)yf, ss, (float4*)out);
}

// Round 10
// 723.110 us; speedup vs baseline: 1.9853x; 1.0870x over previous
//
#include <hip/hip_runtime.h>
#include <hip/hip_bf16.h>

constexpr int NN    = 30000;   // total nodes
constexpr int NCELL = 66;
constexpr int NF    = 256;     // features
constexpr float EPS = 1e-5f;

using bf16x8 = __attribute__((ext_vector_type(8))) short;   // 8 bf16 = 4 VGPRs
using f32x4  = __attribute__((ext_vector_type(4))) float;

__device__ __forceinline__ float bf2f(unsigned short u) {
    return __uint_as_float(((unsigned)u) << 16);
}
__device__ __forceinline__ unsigned short f2bf(float f) {
    __hip_bfloat16 h = __float2bfloat16(f);   // RNE
    return *reinterpret_cast<unsigned short*>(&h);
}
// accumulate 8 bf16 features packed in a float4 (bit halves), f32 math
__device__ __forceinline__ void acc8(float* acc, float4 u, float w) {
    unsigned a = __float_as_uint(u.x), b = __float_as_uint(u.y);
    unsigned c = __float_as_uint(u.z), d = __float_as_uint(u.w);
    acc[0] += w * __uint_as_float(a << 16);
    acc[1] += w * __uint_as_float(a & 0xffff0000u);
    acc[2] += w * __uint_as_float(b << 16);
    acc[3] += w * __uint_as_float(b & 0xffff0000u);
    acc[4] += w * __uint_as_float(c << 16);
    acc[5] += w * __uint_as_float(c & 0xffff0000u);
    acc[6] += w * __uint_as_float(d << 16);
    acc[7] += w * __uint_as_float(d & 0xffff0000u);
}

// ---------------- init: packed hist = 0, fill/sums = 0 ----------------
__global__ void k_init(unsigned long long* packed, int* fill, float* sums) {
    int i = blockIdx.x * 256 + threadIdx.x;
    if (i < NN) { packed[i] = 0ull; fill[i] = 0; }
    if (i < 2 * NF) sums[i] = 0.0f;
}

__global__ void k_zero_stats(float* sums) {
    int i = threadIdx.x;
    if (i < 2 * NF) sums[i] = 0.0f;
}

// ---------------- concat (cell ++ sub) f32 -> bf16 ----------------
__global__ void k_concat_h(const float4* __restrict__ cell, const float4* __restrict__ sub,
                           ushort4* __restrict__ xh) {
    int idx = blockIdx.x * 256 + threadIdx.x;          // float4 index
    if (idx >= NN * (NF / 4)) return;
    const int CELL4 = NCELL * (NF / 4);
    float4 v = (idx < CELL4) ? cell[idx] : sub[idx - CELL4];
    ushort4 o;
    o.x = f2bf(v.x); o.y = f2bf(v.y); o.z = f2bf(v.z); o.w = f2bf(v.w);
    xh[idx] = o;
}

// ---------------- convert W (f32, o-major k-contig) -> bf16 ----------------
__global__ void k_cvtw(const float4* __restrict__ W, ushort4* __restrict__ Wh) {
    int idx = blockIdx.x * 256 + threadIdx.x;
    if (idx >= NF * NF / 4) return;
    float4 v = W[idx];
    ushort4 o;
    o.x = f2bf(v.x); o.y = f2bf(v.y); o.z = f2bf(v.z); o.w = f2bf(v.w);
    Wh[idx] = o;
}

// ------- degree + per-col edge counts: ONE u64 atomic/edge --------------------
// bits [40:63] = edge count, bits [0:39] = sum(ew * 2^24) (max ~2^31, no ovf)
__global__ void k_pass1(const int* __restrict__ ei, const float* __restrict__ ew,
                        unsigned long long* packed, int E) {
    int e = blockIdx.x * 256 + threadIdx.x;
    if (e >= E) return;
    int col = ei[E + e];
    unsigned long long p = (1ull << 40) |
        (unsigned long long)__float2uint_rn(ew[e] * 16777216.0f);
    atomicAdd(&packed[col], p);
}

// unpack: deg = 1 + fixsum/2^24 ; counts for scan
__global__ void k_dinv(const unsigned long long* __restrict__ packed,
                       float* __restrict__ dinv, int* __restrict__ counts) {
    int i = blockIdx.x * 256 + threadIdx.x;
    if (i >= NN) return;
    unsigned long long p = packed[i];
    counts[i] = (int)(p >> 40);
    float deg = 1.0f + (float)((double)(p & 0xFFFFFFFFFFull) * 5.9604644775390625e-8);
    dinv[i] = rsqrtf(deg);             // deg >= 1 always (self loop)
}

// ---------------- exclusive prefix sum of counts -> col_ptr (single block) --------
__global__ void k_scan(const int* __restrict__ counts, int* __restrict__ col_ptr) {
    __shared__ int part[256];
    __shared__ int pref[257];
    int t = threadIdx.x;
    const int CH = (NN + 255) / 256;   // 118
    int beg = t * CH;
    int end = beg + CH; if (end > NN) end = NN;
    int s = 0;
    for (int i = beg; i < end; i++) s += counts[i];
    part[t] = s;
    __syncthreads();
    if (t == 0) {
        int r = 0;
        for (int i = 0; i < 256; i++) { pref[i] = r; r += part[i]; }
        pref[256] = r;
    }
    __syncthreads();
    int run = pref[t];
    for (int i = beg; i < end; i++) { col_ptr[i] = run; run += counts[i]; }
    if (t == 255) col_ptr[NN] = pref[256];
}

// ---------------- scatter edges into CSR (sorted by col), compute norm ------------
__global__ void k_scatter(const int* __restrict__ ei, const float* __restrict__ ew,
                          const float* __restrict__ dinv, const int* __restrict__ col_ptr,
                          int* fill, int* __restrict__ rs, float* __restrict__ ns, int E) {
    int e = blockIdx.x * 256 + threadIdx.x;
    if (e >= E) return;
    int row = ei[e];
    int col = ei[E + e];
    float nrm = dinv[row] * ew[e] * dinv[col];
    int pos = col_ptr[col] + atomicAdd(&fill[col], 1);
    rs[pos] = row;
    ns[pos] = nrm;
}

// ------------- one hop: y = A_hat x, bf16 in/out, f32 accum ------------------------
// 1 wave per node; 32 lanes span the 512B row (16B/lane); halves process even/odd
// edges => 2 edges per load instr; pair-loop unrolled x8 => 16 edges in flight.
__global__ __launch_bounds__(256) void k_prop(const ushort* __restrict__ xin,
                                              ushort* __restrict__ xout,
                                              const int* __restrict__ col_ptr,
                                              const int* __restrict__ rs,
                                              const float* __restrict__ ns,
                                              const float* __restrict__ dinv) {
    int n = blockIdx.x * 4 + (threadIdx.x >> 6);
    int lane = threadIdx.x & 63;
    int half = lane >> 5;              // 0: even edges, 1: odd edges
    int fb = lane & 31;                // features fb*8 .. fb*8+7
    const float4* xrow = (const float4*)xin;    // row r = x4[r*32 + fb]
    int beg = col_ptr[n], end = col_ptr[n + 1];
    int cnt = end - beg;
    float acc[8];
    #pragma unroll
    for (int i = 0; i < 8; i++) acc[i] = 0.f;
    int steps = cnt >> 1;
    int it = 0;
    int e = beg + half;
    for (; it + 8 <= steps; it += 8, e += 16) {
        int   s0 = rs[e],      s1 = rs[e + 2],  s2 = rs[e + 4],  s3 = rs[e + 6];
        int   s4 = rs[e + 8],  s5 = rs[e + 10], s6 = rs[e + 12], s7 = rs[e + 14];
        float w0 = ns[e],      w1 = ns[e + 2],  w2 = ns[e + 4],  w3 = ns[e + 6];
        float w4 = ns[e + 8],  w5 = ns[e + 10], w6 = ns[e + 12], w7 = ns[e + 14];
        float4 u0 = xrow[s0 * 32 + fb];
        float4 u1 = xrow[s1 * 32 + fb];
        float4 u2 = xrow[s2 * 32 + fb];
        float4 u3 = xrow[s3 * 32 + fb];
        float4 u4 = xrow[s4 * 32 + fb];
        float4 u5 = xrow[s5 * 32 + fb];
        float4 u6 = xrow[s6 * 32 + fb];
        float4 u7 = xrow[s7 * 32 + fb];
        acc8(acc, u0, w0); acc8(acc, u1, w1); acc8(acc, u2, w2); acc8(acc, u3, w3);
        acc8(acc, u4, w4); acc8(acc, u5, w5); acc8(acc, u6, w6); acc8(acc, u7, w7);
    }
    for (; it + 4 <= steps; it += 4, e += 8) {
        int   s0 = rs[e],     s1 = rs[e + 2], s2 = rs[e + 4], s3 = rs[e + 6];
        float w0 = ns[e],     w1 = ns[e + 2], w2 = ns[e + 4], w3 = ns[e + 6];
        float4 u0 = xrow[s0 * 32 + fb];
        float4 u1 = xrow[s1 * 32 + fb];
        float4 u2 = xrow[s2 * 32 + fb];
        float4 u3 = xrow[s3 * 32 + fb];
        acc8(acc, u0, w0); acc8(acc, u1, w1); acc8(acc, u2, w2); acc8(acc, u3, w3);
    }
    for (; it < steps; ++it, e += 2) {
        int s0 = rs[e]; float w0 = ns[e];
        float4 u0 = xrow[s0 * 32 + fb];
        acc8(acc, u0, w0);
    }
    if ((cnt & 1) && half == 0) {          // odd remainder edge
        int el = beg + cnt - 1;
        float4 u0 = xrow[rs[el] * 32 + fb];
        acc8(acc, u0, ns[el]);
    }
    #pragma unroll
    for (int i = 0; i < 8; i++) acc[i] += __shfl_xor(acc[i], 32);
    if (half == 0) {
        float dn = dinv[n];
        float4 u = xrow[n * 32 + fb];
        acc8(acc, u, dn * dn);             // self loop
        unsigned p0 = ((unsigned)f2bf(acc[1]) << 16) | f2bf(acc[0]);
        unsigned p1 = ((unsigned)f2bf(acc[3]) << 16) | f2bf(acc[2]);
        unsigned p2 = ((unsigned)f2bf(acc[5]) << 16) | f2bf(acc[4]);
        unsigned p3 = ((unsigned)f2bf(acc[7]) << 16) | f2bf(acc[6]);
        float4 o;
        o.x = __uint_as_float(p0); o.y = __uint_as_float(p1);
        o.z = __uint_as_float(p2); o.w = __uint_as_float(p3);
        ((float4*)xout)[n * 32 + fb] = o;
    }
}

// ------- y[m][o] = PReLU(bias[o] + sum_k A[m][k] W[o][k]) -> f32, + BN stats ------
// r9-verified: wave = 16 rows x full 256 cols (acc[16]); stats via LDS block-reduce
// (4 waves) -> 512 atomics/block. Invalid pad wave guarded (no early return).
__global__ __launch_bounds__(256) void k_gemm_fused(const short* __restrict__ A,  // NN x 256 bf16
                                                    const short* __restrict__ B,  // 256 x 256 bf16 (W)
                                                    const float* __restrict__ bias,
                                                    const float* __restrict__ pw,
                                                    float* __restrict__ y,        // NN x 256 f32
                                                    float* __restrict__ sums) {
    constexpr int RT = NN / 16;        // 1875 row tiles
    int w    = threadIdx.x >> 6;       // wave in block
    int lane = threadIdx.x & 63;
    int rt   = blockIdx.x * 4 + w;     // 4 row tiles per block
    int ml   = lane & 15;              // row in tile (A) / col in 16-tile (B, D)
    int q    = lane >> 4;              // quad: A/B k = q*8+j, D row = q*4+r
    bool valid = rt < RT;
    __shared__ float red[2][4][NF];    // [s|s2][wave][col] = 8 KB
    f32x4 acc[16];
    #pragma unroll
    for (int i = 0; i < 16; i++) acc[i] = (f32x4){0.f, 0.f, 0.f, 0.f};
    if (valid) {
        const short* arow = A + (rt * 16 + ml) * NF + q * 8;
        #pragma unroll
        for (int ks = 0; ks < 8; ks++) {
            bf16x8 a = *(const bf16x8*)(arow + ks * 32);
            #pragma unroll
            for (int nt = 0; nt < 16; nt++) {
                bf16x8 b = *(const bf16x8*)(B + (nt * 16 + ml) * NF + ks * 32 + q * 8);
                acc[nt] = __builtin_amdgcn_mfma_f32_16x16x32_bf16(a, b, acc[nt], 0, 0, 0);
            }
        }
    }
    #pragma unroll
    for (int nt = 0; nt < 16; nt++) {
        int col = nt * 16 + ml;
        float s = 0.f, s2 = 0.f;
        if (valid) {
            float bb = bias[col];
            float pc = pw[col];
            #pragma unroll
            for (int r = 0; r < 4; r++) {
                float v = acc[nt][r] + bb;
                v = (v >= 0.f) ? v : pc * v;
                s += v; s2 += v * v;
                y[(rt * 16 + q * 4 + r) * NF + col] = v;
            }
        }
        s  += __shfl_xor(s, 16);  s  += __shfl_xor(s, 32);
        s2 += __shfl_xor(s2, 16); s2 += __shfl_xor(s2, 32);
        if (lane < 16) { red[0][w][col] = s; red[1][w][col] = s2; }
    }
    __syncthreads();
    int t = threadIdx.x;               // t = col, all 256 threads
    float v0 = red[0][0][t] + red[0][1][t] + red[0][2][t] + red[0][3][t];
    float v1 = red[1][0][t] + red[1][1][t] + red[1][2][t] + red[1][3][t];
    atomicAdd(&sums[t], v0);
    atomicAdd(&sums[NF + t], v1);
}

// ---------------- finalize BN scale/shift ----------------
__global__ void k_finalize(const float* __restrict__ sums, const float* __restrict__ gamma,
                           const float* __restrict__ beta, float* __restrict__ ss) {
    int t = threadIdx.x;
    float mean = sums[t] / (float)NN;
    float var = sums[NF + t] / (float)NN - mean * mean;
    if (var < 0.f) var = 0.f;
    float istd = rsqrtf(var + EPS);
    float sc = gamma[t] * istd;
    ss[t] = sc;
    ss[NF + t] = beta[t] - mean * sc;
}

// ---------------- apply BN: f32 y -> bf16 x (feeds next prop chain) ----------------
__global__ void k_apply_h(const float4* __restrict__ y, const float* __restrict__ ss,
                          ushort4* __restrict__ xh) {
    int idx = blockIdx.x * 256 + threadIdx.x;          // float4 index
    if (idx >= NN * (NF / 4)) return;
    int f = (idx & 63) * 4;
    float4 v = y[idx];
    ushort4 o;
    o.x = f2bf(v.x * ss[f]     + ss[NF + f]);
    o.y = f2bf(v.y * ss[f + 1] + ss[NF + f + 1]);
    o.z = f2bf(v.z * ss[f + 2] + ss[NF + f + 2]);
    o.w = f2bf(v.w * ss[f + 3] + ss[NF + f + 3]);
    xh[idx] = o;
}

// ---------------- apply BN: f32 y -> f32 output ----------------
__global__ void k_apply_out(const float4* __restrict__ y, const float* __restrict__ ss,
                            float4* __restrict__ out) {
    int idx = blockIdx.x * 256 + threadIdx.x;          // float4 index
    if (idx >= NN * (NF / 4)) return;
    int f = (idx & 63) * 4;
    float4 v = y[idx];
    float4 o;
    o.x = v.x * ss[f]     + ss[NF + f];
    o.y = v.y * ss[f + 1] + ss[NF + f + 1];
    o.z = v.z * ss[f + 2] + ss[NF + f + 2];
    o.w = v.w * ss[f + 3] + ss[NF + f + 3];
    out[idx] = o;
}

extern "C" void kernel_launch(void* const* d_in, const int* in_sizes, int n_in,
                              void* d_out, int out_size, void* d_ws, size_t ws_size,
                              hipStream_t stream) {
    const float* cell  = (const float*)d_in[0];
    const float* sub   = (const float*)d_in[1];
    const int*   ei    = (const int*)  d_in[2];
    const float* ew    = (const float*)d_in[3];
    const float* W1    = (const float*)d_in[4];
    const float* bias1 = (const float*)d_in[5];
    const float* W2    = (const float*)d_in[6];
    const float* bias2 = (const float*)d_in[7];
    const float* pw    = (const float*)d_in[8];
    const float* gamma = (const float*)d_in[9];
    const float* beta  = (const float*)d_in[10];
    float* out = (float*)d_out;        // reference output dtype is float32
    const int E = in_sizes[3];         // 960000 directed edges

    char* ws = (char*)d_ws;
    size_t off = 0;
    auto alloc = [&](size_t bytes) -> void* {
        void* p = ws + off;
        off = (off + bytes + 255) & ~((size_t)255);
        return p;
    };
    ushort* xh0    = (ushort*)alloc((size_t)NN * NF * 2);       // bf16 x ping
    ushort* xh1    = (ushort*)alloc((size_t)NN * NF * 2);       // bf16 x pong
    float*  yf     = (float*) alloc((size_t)NN * NF * 4);       // f32 prelu'd gemm out
    ushort* W1h    = (ushort*)alloc((size_t)NF * NF * 2);
    ushort* W2h    = (ushort*)alloc((size_t)NF * NF * 2);
    unsigned long long* packed = (unsigned long long*)alloc((size_t)NN * 8);
    float*  dinv   = (float*) alloc((size_t)NN * 4);
    int*    counts = (int*)   alloc((size_t)NN * 4);
    int*    col_ptr= (int*)   alloc((size_t)(NN + 1) * 4);
    int*    fill   = (int*)   alloc((size_t)NN * 4);
    int*    rs     = (int*)   alloc((size_t)E * 4);
    float*  ns     = (float*) alloc((size_t)E * 4);
    float*  sums   = (float*) alloc((size_t)2 * NF * 4);
    float*  ss     = (float*) alloc((size_t)2 * NF * 4);

    const int gN  = (NN + 255) / 256;             // 118
    const int gE  = (E + 255) / 256;
    const int gV4 = (NN * NF / 4 + 255) / 256;    // 7500
    const int gW4 = (NF * NF / 4 + 255) / 256;    // 64
    const int gP  = NN / 4;                       // 7500 blocks, 1 wave/node
    const int gG  = (NN / 16 + 3) / 4;            // 469 blocks x 4 waves

    k_init<<<gN, 256, 0, stream>>>(packed, fill, sums);
    k_concat_h<<<gV4, 256, 0, stream>>>((const float4*)cell, (const float4*)sub, (ushort4*)xh0);
    k_cvtw<<<gW4, 256, 0, stream>>>((const float4*)W1, (ushort4*)W1h);
    k_cvtw<<<gW4, 256, 0, stream>>>((const float4*)W2, (ushort4*)W2h);
    k_pass1<<<gE, 256, 0, stream>>>(ei, ew, packed, E);
    k_dinv<<<gN, 256, 0, stream>>>(packed, dinv, counts);
    k_scan<<<1, 256, 0, stream>>>(counts, col_ptr);
    k_scatter<<<gE, 256, 0, stream>>>(ei, ew, dinv, col_ptr, fill, rs, ns, E);

    // ---------------- layer 1 ----------------
    k_prop<<<gP, 256, 0, stream>>>(xh0, xh1, col_ptr, rs, ns, dinv);
    k_prop<<<gP, 256, 0, stream>>>(xh1, xh0, col_ptr, rs, ns, dinv);
    k_prop<<<gP, 256, 0, stream>>>(xh0, xh1, col_ptr, rs, ns, dinv);
    k_gemm_fused<<<gG, 256, 0, stream>>>((const short*)xh1, (const short*)W1h, bias1, pw, yf, sums);
    k_finalize<<<1, 256, 0, stream>>>(sums, gamma, beta, ss);
    k_apply_h<<<gV4, 256, 0, stream>>>((const float4*)yf, ss, (ushort4*)xh0);
    k_zero_stats<<<1, 512, 0, stream>>>(sums);

    // ---------------- layer 2 ----------------
    k_prop<<<gP, 256, 0, stream>>>(xh0, xh1, col_ptr, rs, ns, dinv);
    k_prop<<<gP, 256, 0, stream>>>(xh1, xh0, col_ptr, rs, ns, dinv);
    k_prop<<<gP, 256, 0, stream>>>(xh0, xh1, col_ptr, rs, ns, dinv);
    k_gemm_fused<<<gG, 256, 0, stream>>>((const short*)xh1, (const short*)W2h, bias2, pw, yf, sums);
    k_finalize<<<1, 256, 0, stream>>>(sums, gamma, beta, ss);
    k_apply_out<<<gV4, 256, 0, stream>>>((const float4*)yf, ss, (float4*)out);
}